// Round 1
// 1130.513 us; speedup vs baseline: 1.0645x; 1.0645x over previous
//
#include <hip/hip_runtime.h>
#include <hip/hip_bf16.h>

typedef __bf16 bf16x8 __attribute__((ext_vector_type(8)));
typedef __bf16 bf16x4 __attribute__((ext_vector_type(4)));
typedef float  f32x4  __attribute__((ext_vector_type(4)));

#define N_PTS  65536
#define B_SZ   4
#define P_TOT  (B_SZ * N_PTS)
#define PITCH1 104   // 96 k (67 padded) + 8 pad, bf16 elems
#define PITCH2 136   // 128 k + 8 pad

__device__ __forceinline__ void gload_lds16(const float* g, float* l) {
    __builtin_amdgcn_global_load_lds(
        (const __attribute__((address_space(1))) void*)g,
        (__attribute__((address_space(3))) void*)l,
        16, 0, 0);
}

// ---------------------------------------------------------------------------
// Kernel 1: fused 2-layer bf16-MFMA MLP + grid head.
// v2: 256 points/block (4 tiles of 64) instead of 64 -> 4x fewer blocks, and
// weights staged coalesced -> LDS bf16 -> register fragments (the per-block
// divergent scalar weight gathers of v1 were ~400 us of the old 514 us).
// ---------------------------------------------------------------------------
__global__ __launch_bounds__(256) void mlp_grid_kernel(
    const float* __restrict__ x_loc, const float* __restrict__ x_feat,
    const float* __restrict__ W1, const float* __restrict__ b1,
    const float* __restrict__ W2, const float* __restrict__ b2,
    const float* __restrict__ Wr, const float* __restrict__ br,
    float* __restrict__ grid_out)
{
    __shared__ __align__(16) union SmemU {
        __bf16 wbuf[128 * 128];            // weight staging (W1 then W2), 32 KB
        struct {
            __bf16 stage[64 * PITCH1];     // h0 tile  13.3 KB
            __bf16 h1s[64 * PITCH2];       // h1 tile  17.4 KB
            float  gpart[16][2][64];       // grid partials 8 KB
        } r;
    } u;

    const int tid = threadIdx.x;
    const int w   = tid >> 6;
    const int l   = tid & 63;
    const int q   = l >> 4;
    const int lp  = l & 15;

    // ---- W1 -> LDS bf16 [128][96] (coalesced), then fragments ----
    for (int idx = tid; idx < 128 * 96; idx += 256) {
        const int o = idx / 96;
        const int k = idx - o * 96;
        u.wbuf[idx] = (__bf16)((k < 67) ? W1[o * 67 + k] : 0.0f);
    }
    __syncthreads();
    bf16x8 w1f[2][3];
    #pragma unroll
    for (int i = 0; i < 2; ++i) {
        const int o = (2 * w + i) * 16 + lp;
        #pragma unroll
        for (int ks = 0; ks < 3; ++ks)
            w1f[i][ks] = *(const bf16x8*)&u.wbuf[o * 96 + ks * 32 + q * 8];
    }
    __syncthreads();
    // ---- W2 -> LDS bf16 [128][128], then fragments ----
    for (int idx = tid; idx < 128 * 128; idx += 256)
        u.wbuf[idx] = (__bf16)W2[idx];
    __syncthreads();
    bf16x8 w2f[2][4];
    #pragma unroll
    for (int i = 0; i < 2; ++i) {
        const int o = (2 * w + i) * 16 + lp;
        #pragma unroll
        for (int ks = 0; ks < 4; ++ks)
            w2f[i][ks] = *(const bf16x8*)&u.wbuf[o * 128 + ks * 32 + q * 8];
    }
    // biases / Wr rows (contiguous per wave -> cheap)
    float b1v[2][4], b2v[2][4], wrp[2][2][4];
    #pragma unroll
    for (int i = 0; i < 2; ++i) {
        const int ob = (2 * w + i) * 16 + q * 4;
        #pragma unroll
        for (int r = 0; r < 4; ++r) {
            b1v[i][r]    = b1[ob + r];
            b2v[i][r]    = b2[ob + r];
            wrp[0][i][r] = Wr[0 * 131 + 3 + ob + r];
            wrp[1][i][r] = Wr[1 * 131 + 3 + ob + r];
        }
    }
    __syncthreads();   // wbuf dead; r.* regions live from here

    for (int t = 0; t < 4; ++t) {
        const int pt0 = blockIdx.x * 256 + t * 64;

        // ---- stage h0 = concat(x_loc, x_feat): float4 over n, bf16 to LDS ----
        {
            const int g4  = tid & 15;        // group of 4 points
            const int kk  = tid >> 4;        // channel phase 0..15
            const int ptg = g4 * 4;
            const int pp  = pt0 + ptg;
            const int bb  = pp >> 16;
            const int nn  = pp & 0xFFFF;
            for (int k = kk; k < 96; k += 16) {
                if (k < 67) {
                    const float4 v = (k < 3)
                        ? *(const float4*)&x_loc[((bb * 3 + k) << 16) | nn]
                        : *(const float4*)&x_feat[((bb * 64 + (k - 3)) << 16) | nn];
                    u.r.stage[(ptg + 0) * PITCH1 + k] = (__bf16)v.x;
                    u.r.stage[(ptg + 1) * PITCH1 + k] = (__bf16)v.y;
                    u.r.stage[(ptg + 2) * PITCH1 + k] = (__bf16)v.z;
                    u.r.stage[(ptg + 3) * PITCH1 + k] = (__bf16)v.w;
                } else if (k >= 67) {
                    u.r.stage[(ptg + 0) * PITCH1 + k] = (__bf16)0.0f;
                    u.r.stage[(ptg + 1) * PITCH1 + k] = (__bf16)0.0f;
                    u.r.stage[(ptg + 2) * PITCH1 + k] = (__bf16)0.0f;
                    u.r.stage[(ptg + 3) * PITCH1 + k] = (__bf16)0.0f;
                }
            }
        }
        __syncthreads();

        // ---- layer 1: h1 = relu(W1 h0 + b1) ----
        for (int col = 0; col < 4; ++col) {
            const int pt = col * 16 + lp;
            bf16x8 bfr[3];
            #pragma unroll
            for (int ks = 0; ks < 3; ++ks)
                bfr[ks] = *(const bf16x8*)&u.r.stage[pt * PITCH1 + ks * 32 + q * 8];
            #pragma unroll
            for (int i = 0; i < 2; ++i) {
                f32x4 acc = {0.f, 0.f, 0.f, 0.f};
                #pragma unroll
                for (int ks = 0; ks < 3; ++ks)
                    acc = __builtin_amdgcn_mfma_f32_16x16x32_bf16(w1f[i][ks], bfr[ks], acc, 0, 0, 0);
                bf16x4 hv;
                #pragma unroll
                for (int r = 0; r < 4; ++r)
                    hv[r] = (__bf16)fmaxf(acc[r] + b1v[i][r], 0.0f);
                *(bf16x4*)&u.r.h1s[pt * PITCH2 + (2 * w + i) * 16 + q * 4] = hv;
            }
        }
        __syncthreads();

        // ---- layer 2 + grid partials ----
        for (int col = 0; col < 4; ++col) {
            const int pt = col * 16 + lp;
            bf16x8 bfr[4];
            #pragma unroll
            for (int ks = 0; ks < 4; ++ks)
                bfr[ks] = *(const bf16x8*)&u.r.h1s[pt * PITCH2 + ks * 32 + q * 8];
            float p0 = 0.f, p1 = 0.f;
            #pragma unroll
            for (int i = 0; i < 2; ++i) {
                f32x4 acc = {0.f, 0.f, 0.f, 0.f};
                #pragma unroll
                for (int ks = 0; ks < 4; ++ks)
                    acc = __builtin_amdgcn_mfma_f32_16x16x32_bf16(w2f[i][ks], bfr[ks], acc, 0, 0, 0);
                #pragma unroll
                for (int r = 0; r < 4; ++r) {
                    const float v = fmaxf(acc[r] + b2v[i][r], 0.0f);
                    p0 += wrp[0][i][r] * v;
                    p1 += wrp[1][i][r] * v;
                }
            }
            u.r.gpart[w * 4 + q][0][pt] = p0;
            u.r.gpart[w * 4 + q][1][pt] = p1;
        }
        __syncthreads();

        // ---- final grid reduce ----
        if (tid < 128) {
            const int o  = tid >> 6;
            const int pt = tid & 63;
            const int pp = pt0 + pt;
            const int bb = pp >> 16;
            const int nn = pp & 0xFFFF;
            float s = br[o];
            #pragma unroll
            for (int c = 0; c < 3; ++c)
                s += Wr[o * 131 + c] * x_loc[((bb * 3 + c) << 16) | nn];
            #pragma unroll
            for (int g = 0; g < 16; ++g) s += u.r.gpart[g][o][pt];
            grid_out[o * P_TOT + pp] = s;
        }
        // no trailing barrier needed: next tile's stage/h1s writes are ordered
        // by the next __syncthreads, and stage does not alias gpart.
    }
}

// ---------------------------------------------------------------------------
// Kernel 2: bilinear sampling, v2.
// Old version: 4 address-divergent global gathers per pt-channel ->
// ~57.6 cy per wave-gather (TA address pipe limit), 689 us.
// New: per-block row-bbox of the sampled region (data gives ~66 of 128 rows),
// stage that band into LDS (global_load_lds dwordx4, double-buffered,
// prefetch channel c+1 during gather of c), gather via ds_read_b32.
// Worst case (full 128-row slice) still fits: 2 x 64 KB LDS, 1 block/CU.
// ---------------------------------------------------------------------------
__global__ __launch_bounds__(1024) void sample_kernel(
    const float* __restrict__ m0, const float* __restrict__ m1,
    const float* __restrict__ m2, const float* __restrict__ grid,
    float* __restrict__ out)
{
    __shared__ float sbuf[2][128 * 128];   // 2 x 64 KB double buffer
    __shared__ int redmn[16], redmx[16];

    const int tid  = threadIdx.x;
    const int wv   = tid >> 6;
    const int lane = tid & 63;
    const int p = blockIdx.x * 1024 + tid;
    const int b = p >> 16;
    const int n = p & 0xFFFF;
    const float gx = grid[p];
    const float gy = grid[P_TOT + p];

    float ix = ((gx + 1.0f) * 128.0f - 1.0f) * 0.5f;
    float iy = ((gy + 1.0f) * 128.0f - 1.0f) * 0.5f;
    ix = fminf(fmaxf(ix, 0.0f), 127.0f);
    iy = fminf(fmaxf(iy, 0.0f), 127.0f);
    const float x0f = floorf(ix);
    const float y0f = floorf(iy);
    const float wx = ix - x0f;
    const float wy = iy - y0f;
    const int x0 = (int)x0f, y0 = (int)y0f;
    const int x1 = min(x0 + 1, 127);
    const int y1 = min(y0 + 1, 127);
    const float w00 = (1.f - wy) * (1.f - wx);
    const float w01 = (1.f - wy) * wx;
    const float w10 = wy * (1.f - wx);
    const float w11 = wy * wx;

    // ---- block-wide bbox of touched rows ----
    int mn = y0, mx = y1;
    #pragma unroll
    for (int s = 32; s; s >>= 1) {
        mn = min(mn, __shfl_xor(mn, s));
        mx = max(mx, __shfl_xor(mx, s));
    }
    if (lane == 0) { redmn[wv] = mn; redmx[wv] = mx; }
    __syncthreads();
    #pragma unroll
    for (int i = 0; i < 16; ++i) { mn = min(mn, redmn[i]); mx = max(mx, redmx[i]); }

    int ymin = mn;
    int R = mx - mn + 1;                 // rows to stage
    if (R & 1) { if (ymin > 0) --ymin; ++R; }   // even rows -> whole 1 KB chunks
    const int nchunk = R >> 1;           // 1 KB (256-float) chunks per channel

    const int a00 = (y0 - ymin) * 128 + x0;
    const int d01 = x1 - x0;             // 0 or 1
    const int d10 = (y1 - y0) * 128;     // 0 or 128

    auto slice = [&](int c) -> const float* {
        if (c < 64)  return m0 + ((size_t)(b * 64  + c)         << 14);
        if (c < 192) return m1 + ((size_t)(b * 128 + (c - 64))  << 14);
        return              m2 + ((size_t)(b * 256 + (c - 192)) << 14);
    };
    auto stage = [&](const float* src, int bsel) {
        const float* g = src + ymin * 128 + (lane << 2);
        for (int ch = wv; ch < nchunk; ch += 16)
            gload_lds16(g + (ch << 8), &sbuf[bsel][ch << 8]);
    };

    float* op = out + (size_t)(b * 448) * 65536 + n;

    stage(slice(0), 0);
    for (int c = 0; c < 448; ++c) {
        const int cur = c & 1;
        __syncthreads();                     // drains vmcnt: sbuf[cur] ready; all reads of sbuf[cur^1] done
        if (c + 1 < 448) stage(slice(c + 1), cur ^ 1);   // prefetch overlaps gather
        const float* sb = sbuf[cur];
        const float v00 = sb[a00];
        const float v01 = sb[a00 + d01];
        const float v10 = sb[a00 + d10];
        const float v11 = sb[a00 + d01 + d10];
        const float v = w00 * v00 + w01 * v01 + w10 * v10 + w11 * v11;
        __builtin_nontemporal_store(v, op);
        op += 65536;
    }
}

extern "C" void kernel_launch(void* const* d_in, const int* in_sizes, int n_in,
                              void* d_out, int out_size, void* d_ws, size_t ws_size,
                              hipStream_t stream)
{
    (void)in_sizes; (void)n_in; (void)out_size; (void)ws_size;
    const float* x_loc  = (const float*)d_in[0];
    const float* x_feat = (const float*)d_in[1];
    const float* m0     = (const float*)d_in[2];
    const float* m1     = (const float*)d_in[3];
    const float* m2     = (const float*)d_in[4];
    const float* W1     = (const float*)d_in[5];
    const float* b1     = (const float*)d_in[6];
    const float* W2     = (const float*)d_in[7];
    const float* b2     = (const float*)d_in[8];
    const float* Wr     = (const float*)d_in[9];
    const float* br     = (const float*)d_in[10];
    float* out  = (float*)d_out;
    float* grid = (float*)d_ws;   // gx at [0,P), gy at [P,2P)

    mlp_grid_kernel<<<dim3(P_TOT / 256), dim3(256), 0, stream>>>(
        x_loc, x_feat, W1, b1, W2, b2, Wr, br, grid);
    sample_kernel<<<dim3(P_TOT / 1024), dim3(1024), 0, stream>>>(
        m0, m1, m2, grid, out);
}

// Round 2
// 1076.544 us; speedup vs baseline: 1.1179x; 1.0501x over previous
//
#include <hip/hip_runtime.h>
#include <hip/hip_bf16.h>

typedef __bf16 bf16x8 __attribute__((ext_vector_type(8)));
typedef __bf16 bf16x4 __attribute__((ext_vector_type(4)));
typedef float  f32x4  __attribute__((ext_vector_type(4)));

#define N_PTS  65536
#define B_SZ   4
#define P_TOT  (B_SZ * N_PTS)
#define PITCH1 104            // 96 k + 8 pad (bf16 elems)
#define PITCH2 136            // 128 k + 8 pad
#define CPAD   72             // cropped sampling band width (floats)
#define BUF_F  6144           // 24 KB buffer -> R <= 85 rows
#define NCH    448
#define WP1_ELEMS (8*3*64*8)  // 12288 bf16
#define WP2_ELEMS (8*4*64*8)  // 16384 bf16

__device__ __forceinline__ void gload_lds16(const float* g, float* l) {
    __builtin_amdgcn_global_load_lds(
        (const __attribute__((address_space(1))) void*)g,
        (__attribute__((address_space(3))) void*)l,
        16, 0, 0);
}

// ---------------------------------------------------------------------------
// Kernel 0: one-time repack of W1/W2 into bf16 MFMA A-fragment order in ws.
// Layout: wp[((j*3+ks)*64 + l)*8 + j8]      = W1[j*16+(l&15)][ks*32+(l>>4)*8+j8]
//         wp[WP1 + ((j*4+ks)*64+l)*8 + j8]  = W2[...]
// Fragment loads in the fused kernel become coalesced 16B b128 reads.
// ---------------------------------------------------------------------------
__global__ __launch_bounds__(256) void repack_weights(
    const float* __restrict__ W1, const float* __restrict__ W2,
    __bf16* __restrict__ wp)
{
    const int tid = threadIdx.x;
    for (int idx = tid; idx < WP1_ELEMS; idx += 256) {
        const int j8   = idx & 7;
        const int l    = (idx >> 3) & 63;
        const int rest = idx >> 9;          // j*3 + ks
        const int ks   = rest % 3;
        const int j    = rest / 3;
        const int row  = j * 16 + (l & 15);
        const int k    = ks * 32 + ((l >> 4) << 3) + j8;
        wp[idx] = (__bf16)((k < 67) ? W1[row * 67 + k] : 0.0f);
    }
    for (int idx = tid; idx < WP2_ELEMS; idx += 256) {
        const int j8   = idx & 7;
        const int l    = (idx >> 3) & 63;
        const int rest = idx >> 9;          // j*4 + ks
        const int ks   = rest & 3;
        const int j    = rest >> 2;
        const int row  = j * 16 + (l & 15);
        const int k    = ks * 32 + ((l >> 4) << 3) + j8;
        wp[WP1_ELEMS + idx] = (__bf16)W2[row * 128 + k];
    }
}

// ---------------------------------------------------------------------------
// Fused kernel: 512 pts/block, 512 blocks (2 blocks/CU: LDS ~74 KB, VGPR<=128).
// Phase 1 (MLP): 8 waves x 8 output-channel tiles, 8 rounds of 64 pts; grid
// (gx,gy) lands in per-thread registers via LDS gxy. Head MLP-partials are
// exactly 0 (Wr[:,3:]==0) so the fp32 Wr[:, :3]*x_loc path stays bit-exact.
// Phase 2 (sampling): block bbox -> crop slice to [R][CPAD] band, stage via
// global_load_lds (16B), triple-buffered (stage c+2 during gather of c) so
// the __syncthreads vmcnt(0) drain waits on iteration-old loads; output
// store delayed one channel for the same reason. Uniform fallback to direct
// global gathers if the band ever exceeds the buffer.
// ---------------------------------------------------------------------------
__global__ __launch_bounds__(512, 4) void fused_kernel(
    const float* __restrict__ x_loc, const float* __restrict__ x_feat,
    const float* __restrict__ m0, const float* __restrict__ m1,
    const float* __restrict__ m2,
    const __bf16* __restrict__ wp,
    const float* __restrict__ b1, const float* __restrict__ b2,
    const float* __restrict__ Wr, const float* __restrict__ br,
    float* __restrict__ out)
{
    __shared__ __align__(16) union Smem {
        struct {
            __bf16 stage[64 * PITCH1];   // h0 tile   13.0 KB
            __bf16 h1s[64 * PITCH2];     // h1 tile   17.0 KB
            float  gpart[8][2][64];      //            2.0 KB (wave-reduced)
            float  gxy[2][512];          //            4.0 KB
        } m;
        float sbuf[3][BUF_F];            // 3 x 24 KB sampling buffers
    } u;
    __shared__ int redY0[8], redY1[8], redX0[8], redX1[8];

    const int tid = threadIdx.x;
    const int w   = tid >> 6;        // wave 0..7 = output-channel tile
    const int l   = tid & 63;
    const int q   = l >> 4;
    const int lp  = l & 15;
    const int blk = blockIdx.x;
    const int b   = blk >> 7;        // 128 blocks per batch
    const int n0  = (blk & 127) << 9;

    // ---- weight fragments: coalesced b128 loads from packed ws ----
    bf16x8 w1f[3], w2f[4];
    #pragma unroll
    for (int ks = 0; ks < 3; ++ks)
        w1f[ks] = *(const bf16x8*)&wp[((w * 3 + ks) * 64 + l) * 8];
    #pragma unroll
    for (int ks = 0; ks < 4; ++ks)
        w2f[ks] = *(const bf16x8*)&wp[WP1_ELEMS + ((w * 4 + ks) * 64 + l) * 8];
    float b1v[4], b2v[4], wrp0[4], wrp1[4];
    {
        const int ob = w * 16 + q * 4;
        #pragma unroll
        for (int r = 0; r < 4; ++r) {
            b1v[r]  = b1[ob + r];
            b2v[r]  = b2[ob + r];
            wrp0[r] = Wr[0 * 131 + 3 + ob + r];
            wrp1[r] = Wr[1 * 131 + 3 + ob + r];
        }
    }

    // ================= Phase 1: MLP, 8 rounds of 64 points =================
    for (int t = 0; t < 8; ++t) {
        const int pt0n = n0 + t * 64;

        // stage h0 = concat(x_loc, x_feat) -> LDS bf16 [pt][k]
        {
            const int g4  = tid & 15;
            const int kk  = tid >> 4;           // 0..31
            const int ptg = g4 * 4;
            const int nn  = pt0n + ptg;
            #pragma unroll
            for (int kx = 0; kx < 3; ++kx) {
                const int k = kk + kx * 32;     // covers 0..95
                if (k < 67) {
                    const float4 v = (k < 3)
                        ? *(const float4*)&x_loc[((b * 3 + k) << 16) | nn]
                        : *(const float4*)&x_feat[((b * 64 + (k - 3)) << 16) | nn];
                    u.m.stage[(ptg + 0) * PITCH1 + k] = (__bf16)v.x;
                    u.m.stage[(ptg + 1) * PITCH1 + k] = (__bf16)v.y;
                    u.m.stage[(ptg + 2) * PITCH1 + k] = (__bf16)v.z;
                    u.m.stage[(ptg + 3) * PITCH1 + k] = (__bf16)v.w;
                } else {
                    u.m.stage[(ptg + 0) * PITCH1 + k] = (__bf16)0.0f;
                    u.m.stage[(ptg + 1) * PITCH1 + k] = (__bf16)0.0f;
                    u.m.stage[(ptg + 2) * PITCH1 + k] = (__bf16)0.0f;
                    u.m.stage[(ptg + 3) * PITCH1 + k] = (__bf16)0.0f;
                }
            }
        }
        __syncthreads();

        // layer 1: h1 = relu(W1 h0 + b1)
        for (int col = 0; col < 4; ++col) {
            const int pt = col * 16 + lp;
            bf16x8 bfr[3];
            #pragma unroll
            for (int ks = 0; ks < 3; ++ks)
                bfr[ks] = *(const bf16x8*)&u.m.stage[pt * PITCH1 + ks * 32 + q * 8];
            f32x4 acc = {0.f, 0.f, 0.f, 0.f};
            #pragma unroll
            for (int ks = 0; ks < 3; ++ks)
                acc = __builtin_amdgcn_mfma_f32_16x16x32_bf16(w1f[ks], bfr[ks], acc, 0, 0, 0);
            bf16x4 hv;
            #pragma unroll
            for (int r = 0; r < 4; ++r)
                hv[r] = (__bf16)fmaxf(acc[r] + b1v[r], 0.0f);
            *(bf16x4*)&u.m.h1s[pt * PITCH2 + w * 16 + q * 4] = hv;
        }
        __syncthreads();

        // layer 2 + head partials (wave-reduced over q via shfl)
        for (int col = 0; col < 4; ++col) {
            const int pt = col * 16 + lp;
            bf16x8 bfr[4];
            #pragma unroll
            for (int ks = 0; ks < 4; ++ks)
                bfr[ks] = *(const bf16x8*)&u.m.h1s[pt * PITCH2 + ks * 32 + q * 8];
            f32x4 acc = {0.f, 0.f, 0.f, 0.f};
            #pragma unroll
            for (int ks = 0; ks < 4; ++ks)
                acc = __builtin_amdgcn_mfma_f32_16x16x32_bf16(w2f[ks], bfr[ks], acc, 0, 0, 0);
            float p0 = 0.f, p1 = 0.f;
            #pragma unroll
            for (int r = 0; r < 4; ++r) {
                const float v = fmaxf(acc[r] + b2v[r], 0.0f);
                p0 += wrp0[r] * v;
                p1 += wrp1[r] * v;
            }
            p0 += __shfl_xor(p0, 16); p0 += __shfl_xor(p0, 32);
            p1 += __shfl_xor(p1, 16); p1 += __shfl_xor(p1, 32);
            if (q == 0) {
                u.m.gpart[w][0][pt] = p0;
                u.m.gpart[w][1][pt] = p1;
            }
        }
        __syncthreads();

        // grid reduce -> gxy
        if (tid < 128) {
            const int o  = tid >> 6;
            const int pt = tid & 63;
            const int nn = pt0n + pt;
            float s = br[o];
            #pragma unroll
            for (int c = 0; c < 3; ++c)
                s += Wr[o * 131 + c] * x_loc[((b * 3 + c) << 16) | nn];
            #pragma unroll
            for (int g = 0; g < 8; ++g) s += u.m.gpart[g][o][pt];
            u.m.gxy[o][t * 64 + pt] = s;
        }
        // no trailing barrier: next round's stage/L1 barriers order gpart reuse
    }
    __syncthreads();

    // ================= Phase 2: bilinear sampling =================
    const float gx = u.m.gxy[0][tid];
    const float gy = u.m.gxy[1][tid];
    const int n = n0 + tid;

    float ix = ((gx + 1.0f) * 128.0f - 1.0f) * 0.5f;
    float iy = ((gy + 1.0f) * 128.0f - 1.0f) * 0.5f;
    ix = fminf(fmaxf(ix, 0.0f), 127.0f);
    iy = fminf(fmaxf(iy, 0.0f), 127.0f);
    const float x0f = floorf(ix);
    const float y0f = floorf(iy);
    const float wx = ix - x0f;
    const float wy = iy - y0f;
    const int x0 = (int)x0f, y0 = (int)y0f;
    const int x1 = min(x0 + 1, 127);
    const int y1 = min(y0 + 1, 127);
    const float w00 = (1.f - wy) * (1.f - wx);
    const float w01 = (1.f - wy) * wx;
    const float w10 = wy * (1.f - wx);
    const float w11 = wy * wx;

    // block-wide bbox (y and x)
    int mnY = y0, mxY = y1, mnX = x0, mxX = x1;
    #pragma unroll
    for (int s = 32; s; s >>= 1) {
        mnY = min(mnY, __shfl_xor(mnY, s));
        mxY = max(mxY, __shfl_xor(mxY, s));
        mnX = min(mnX, __shfl_xor(mnX, s));
        mxX = max(mxX, __shfl_xor(mxX, s));
    }
    if (l == 0) { redY0[w] = mnY; redY1[w] = mxY; redX0[w] = mnX; redX1[w] = mxX; }
    __syncthreads();   // also orders gxy reads before sbuf overwrites
    #pragma unroll
    for (int i = 0; i < 8; ++i) {
        mnY = min(mnY, redY0[i]); mxY = max(mxY, redY1[i]);
        mnX = min(mnX, redX0[i]); mxX = max(mxX, redX1[i]);
    }

    const int ymin  = mnY;
    const int R     = mxY - mnY + 1;
    const int xminA = mnX & ~3;            // keep 16B alignment of staging
    const int width = mxX - xminA + 1;
    const bool ok   = (width <= CPAD) && (R * CPAD <= BUF_F);

    auto slice_ptr = [&](int c) -> const float* {
        if (c < 64)  return m0 + ((size_t)(b * 64  + c)         << 14);
        if (c < 192) return m1 + ((size_t)(b * 128 + (c - 64))  << 14);
        return              m2 + ((size_t)(b * 256 + (c - 192)) << 14);
    };

    float* op = out + ((size_t)(b * 448) << 16) + n;

    if (ok) {
        const int nchunk = (R * CPAD + 255) >> 8;     // 1 KB chunks per channel
        const int a00 = (y0 - ymin) * CPAD + (x0 - xminA);
        const int d01 = x1 - x0;                      // 0 or 1
        const int d10 = (y1 - y0) * CPAD;             // 0 or CPAD

        auto stage = [&](int c, int bsel) {
            const float* sp   = slice_ptr(c);
            const float* src  = sp + ymin * 128 + xminA;
            const float* gend = sp + 16384 - 4;       // per-lane OOB clamp
            for (int ch = w; ch < nchunk; ch += 8) {
                const int o   = (ch << 8) + (l << 2);
                const int row = o / CPAD;             // const-div -> magic mul
                const int col = o - row * CPAD;
                const float* g = src + row * 128 + col;
                if (g > gend) g = gend;
                gload_lds16(g, &u.sbuf[bsel][ch << 8]);
            }
        };

        stage(0, 0);
        stage(1, 1);
        float vprev = 0.f;
        float* opprev = op;
        int cur = 0, nst = 2;
        for (int c = 0; c < NCH; ++c) {
            __syncthreads();      // vmcnt(0): drains iteration-old loads/stores
            if (c) __builtin_nontemporal_store(vprev, opprev);
            if (c + 2 < NCH) stage(c + 2, nst);
            const float* sb = &u.sbuf[cur][0];
            const float v00 = sb[a00];
            const float v01 = sb[a00 + d01];
            const float v10 = sb[a00 + d10];
            const float v11 = sb[a00 + d01 + d10];
            vprev  = w00 * v00 + w01 * v01 + w10 * v10 + w11 * v11;
            opprev = op;
            op += N_PTS;
            cur = (cur == 2) ? 0 : cur + 1;
            nst = (nst == 2) ? 0 : nst + 1;
        }
        __builtin_nontemporal_store(vprev, opprev);
    } else {
        // correctness fallback: direct global gathers (never hit with this data)
        const int o00 = y0 * 128 + x0;
        const int o01 = y0 * 128 + x1;
        const int o10 = y1 * 128 + x0;
        const int o11 = y1 * 128 + x1;
        for (int c = 0; c < NCH; ++c) {
            const float* sp = slice_ptr(c);
            const float v = w00 * sp[o00] + w01 * sp[o01]
                          + w10 * sp[o10] + w11 * sp[o11];
            __builtin_nontemporal_store(v, op);
            op += N_PTS;
        }
    }
}

extern "C" void kernel_launch(void* const* d_in, const int* in_sizes, int n_in,
                              void* d_out, int out_size, void* d_ws, size_t ws_size,
                              hipStream_t stream)
{
    (void)in_sizes; (void)n_in; (void)out_size; (void)ws_size;
    const float* x_loc  = (const float*)d_in[0];
    const float* x_feat = (const float*)d_in[1];
    const float* m0     = (const float*)d_in[2];
    const float* m1     = (const float*)d_in[3];
    const float* m2     = (const float*)d_in[4];
    const float* W1     = (const float*)d_in[5];
    const float* b1     = (const float*)d_in[6];
    const float* W2     = (const float*)d_in[7];
    const float* b2     = (const float*)d_in[8];
    const float* Wr     = (const float*)d_in[9];
    const float* br     = (const float*)d_in[10];
    float*  out = (float*)d_out;
    __bf16* wpk = (__bf16*)d_ws;   // packed weight fragments, ~56 KB

    repack_weights<<<dim3(1), dim3(256), 0, stream>>>(W1, W2, wpk);
    fused_kernel<<<dim3(P_TOT / 512), dim3(512), 0, stream>>>(
        x_loc, x_feat, m0, m1, m2, wpk, b1, b2, Wr, br, out);
}